// Round 7
// baseline (1902.709 us; speedup 1.0000x reference)
//
#include <hip/hip_runtime.h>
#include <stdint.h>

// FFJORD block: B=2048, D=512, H=1024, 9 RK38 steps x 4 stages, 2 Hutchinson probes.
// f32 in/out. bf16 MFMA GEMMs, f32 accumulate, fp32 RK state.
// PRNG: JAX threefry, jax_threefry_partitionable=True (default since 0.4.30), x64 off:
//   split(key,n)[i] = threefry(key, (0,i)) (both words)
//   fold_in(key, d) = threefry(key, (0,d))
//   random_bits 32b at flat index p = bits1 ^ bits2 of threefry(key, (0,p))  [XOR!]
//   randint(0,2): lsb of lower_bits under k2 = split(folded,2)[1].

#define B_N 2048
#define D_N 512
#define H_N 1024
#define BD (B_N * D_N)

typedef unsigned short u16;
typedef __attribute__((ext_vector_type(8))) short s16x8;   // 8 x bf16
typedef __attribute__((ext_vector_type(4))) float f32x4;   // MFMA accumulator

typedef __attribute__((address_space(1))) const uint32_t ga_u32;
typedef __attribute__((address_space(3))) uint32_t ls_u32;

__device__ __forceinline__ float bf2f(u16 u) {
  union { uint32_t u; float f; } c; c.u = ((uint32_t)u) << 16; return c.f;
}
__device__ __forceinline__ u16 f2bf(float f) {
  union { float f; uint32_t u; } c; c.f = f;
  uint32_t r = c.u + 0x7FFFu + ((c.u >> 16) & 1u);  // RTNE
  return (u16)(r >> 16);
}

struct U2 { uint32_t x, y; };

// Threefry-2x32, 20 rounds — KAT-verified: key(0,0) ctr(0,0) -> 6b200159, 99ba4efe.
__device__ __forceinline__ U2 tf2x32(uint32_t k0, uint32_t k1, uint32_t x0, uint32_t x1) {
  uint32_t k2 = k0 ^ k1 ^ 0x1BD11BDAu;
#define ROTL(a, r) (((a) << (r)) | ((a) >> (32 - (r))))
#define RND(r) { x0 += x1; x1 = ROTL(x1, r); x1 ^= x0; }
  x0 += k0; x1 += k1;
  RND(13) RND(15) RND(26) RND(6)
  x0 += k1; x1 += k2 + 1u;
  RND(17) RND(29) RND(16) RND(24)
  x0 += k2; x1 += k0 + 2u;
  RND(13) RND(15) RND(26) RND(6)
  x0 += k0; x1 += k1 + 3u;
  RND(17) RND(29) RND(16) RND(24)
  x0 += k1; x1 += k2 + 4u;
  RND(13) RND(15) RND(26) RND(6)
  x0 += k2; x1 += k0 + 5u;
#undef RND
#undef ROTL
  U2 r; r.x = x0; r.y = x1; return r;
}

// Partitionable key schedule:
//   carry_{s+1} = tf(carry_s, (0,0));  k_stage(st) = tf(carry_s, (0, st+1))
//   folded = tf(k_stage, (0, probe));  k2 = tf(folded, (0,1))
__global__ void k_keysched(uint32_t* __restrict__ ekeys) {
  if (threadIdx.x != 0 || blockIdx.x != 0) return;
  uint32_t kx = 0u, ky = 1234u;  // jax.random.key(1234) -> (0, 1234)
  for (int s = 0; s < 9; ++s) {
    for (int st = 0; st < 4; ++st) {
      U2 kst = tf2x32(kx, ky, 0u, (uint32_t)(st + 1));   // split(key,5)[st+1]
      for (int pr = 0; pr < 2; ++pr) {
        U2 fo = tf2x32(kst.x, kst.y, 0u, (uint32_t)pr);  // fold_in(kst, pr)
        U2 k2 = tf2x32(fo.x, fo.y, 0u, 1u);              // split(folded,2)[1]
        ekeys[(s * 4 + st) * 4 + pr * 2 + 0] = k2.x;
        ekeys[(s * 4 + st) * 4 + pr * 2 + 1] = k2.y;
      }
    }
    U2 c = tf2x32(kx, ky, 0u, 0u);                       // split(key,5)[0] = new carry
    kx = c.x; ky = c.y;
  }
}

// Packed Rademacher bits: e_p = lsb( bits1 ^ bits2 ) of threefry(k2, (0, p)).
// (Partitionable random_bits, bit_width 32: return bits1 ^ bits2.)
__global__ void k_ebits(uint32_t* __restrict__ eb, const uint32_t* __restrict__ ek) {
  int t = blockIdx.x * 256 + threadIdx.x;   // 65536 threads
  int probe = t >> 15, idx = t & 32767;
  uint32_t p0 = (uint32_t)idx * 32;
  uint32_t k0 = ek[probe * 2], k1 = ek[probe * 2 + 1];
  uint32_t bits = 0;
  for (int j = 0; j < 32; ++j) {
    U2 r = tf2x32(k0, k1, 0u, p0 + j);
    bits |= ((r.x ^ r.y) & 1u) << j;      // <-- xor combine (bit_width=32 path)
  }
  eb[probe * 32768 + idx] = bits;
}

__global__ void k_init(const float* __restrict__ x, float* __restrict__ z, u16* __restrict__ zin,
                       float* __restrict__ lp, float* __restrict__ d0, float* __restrict__ d1) {
  int i = blockIdx.x * 256 + threadIdx.x;
  if (i < BD) { float v = x[i]; z[i] = v; zin[i] = f2bf(v); }
  if (i < B_N) { lp[i] = 0.f; d0[i] = 0.f; d1[i] = 0.f; }
}

// f32 (R x C) -> bf16 transposed (C x R)
__global__ void k_cvtT(const float* __restrict__ src, u16* __restrict__ dst, int R, int C) {
  int i = blockIdx.x * 256 + threadIdx.x;
  if (i >= R * C) return;
  int c = i / R, r = i - c * R;
  dst[i] = f2bf(src[(size_t)r * C + c]);
}
// f32 -> bf16 direct
__global__ void k_cvt(const float* __restrict__ src, u16* __restrict__ dst, int n) {
  int i = blockIdx.x * 256 + threadIdx.x;
  if (i < n) dst[i] = f2bf(src[i]);
}

__global__ void k_sentinel(float* __restrict__ out, int n) {
  int i = blockIdx.x * 256 + threadIdx.x;
  if (i < n) out[i] = 12345.0f;
}

// Fused 5-product GEMM over (b,h) tiles of 64x64, K=D=512:
//   az = zin@W1, au* = e*@W1, av* = e*@W2^T  (W2b natural HxD = NxK form)
// Epilogue: h=tanh(az+b1+t*tw1)->hbuf(bf16); s=1-h^2 (f32); atomic div[b]+=sum s*u*v.
__global__ __launch_bounds__(256)
void k_f1(const u16* __restrict__ zin, const uint32_t* __restrict__ eb,
          const u16* __restrict__ W1T, const u16* __restrict__ W2b,
          const float* __restrict__ b1, const float* __restrict__ tw1, float tstage,
          u16* __restrict__ hbuf, float* __restrict__ div0, float* __restrict__ div1) {
  __shared__ u16 Zs[64 * 32], W1s[64 * 32], W2s[64 * 32];
  const int tid = threadIdx.x, wave = tid >> 6, lane = tid & 63;
  const int bm = blockIdx.x >> 4;        // H/64 = 16 col tiles
  const int bh = blockIdx.x & 15;
  const int row0 = bm * 64, col0 = bh * 64;
  const int wm = wave >> 1, wn = wave & 1, r16 = lane & 15, q = lane >> 4;
  const int srow = lane >> 2, scol = (lane & 3) * 8;

  f32x4 az[2][2], au0[2][2], au1[2][2], av0[2][2], av1[2][2];
#pragma unroll
  for (int i = 0; i < 2; ++i)
#pragma unroll
    for (int j = 0; j < 2; ++j) {
      az[i][j] = (f32x4){0,0,0,0}; au0[i][j] = (f32x4){0,0,0,0}; au1[i][j] = (f32x4){0,0,0,0};
      av0[i][j] = (f32x4){0,0,0,0}; av1[i][j] = (f32x4){0,0,0,0};
    }

  for (int kt = 0; kt < 512; kt += 32) {
    const u16* gz = zin + (size_t)(row0 + wave * 16 + srow) * 512 + kt + scol;
    const u16* g1 = W1T + (size_t)(col0 + wave * 16 + srow) * 512 + kt + scol;
    const u16* g2 = W2b + (size_t)(col0 + wave * 16 + srow) * 512 + kt + scol;
    __builtin_amdgcn_global_load_lds((ga_u32*)gz, (ls_u32*)(Zs  + wave * 512), 16, 0, 0);
    __builtin_amdgcn_global_load_lds((ga_u32*)g1, (ls_u32*)(W1s + wave * 512), 16, 0, 0);
    __builtin_amdgcn_global_load_lds((ga_u32*)g2, (ls_u32*)(W2s + wave * 512), 16, 0, 0);

    // e fragments from packed bits (A layout: m=lane&15, k=q*8+j)
    s16x8 e0f[2], e1f[2];
#pragma unroll
    for (int i = 0; i < 2; ++i) {
      int r = row0 + wm * 32 + i * 16 + r16;
      uint32_t w0 = eb[r * 16 + (kt >> 5)];
      uint32_t w1 = eb[32768 + r * 16 + (kt >> 5)];
#pragma unroll
      for (int j = 0; j < 8; ++j) {
        e0f[i][j] = (short)(((w0 >> (q * 8 + j)) & 1u) ? 0x3F80 : 0xBF80);
        e1f[i][j] = (short)(((w1 >> (q * 8 + j)) & 1u) ? 0x3F80 : 0xBF80);
      }
    }
    __syncthreads();
    s16x8 zf[2], w1f[2], w2f[2];
#pragma unroll
    for (int i = 0; i < 2; ++i)
      zf[i] = *(const s16x8*)(Zs + (wm * 32 + i * 16 + r16) * 32 + q * 8);
#pragma unroll
    for (int j = 0; j < 2; ++j) {
      w1f[j] = *(const s16x8*)(W1s + (wn * 32 + j * 16 + r16) * 32 + q * 8);
      w2f[j] = *(const s16x8*)(W2s + (wn * 32 + j * 16 + r16) * 32 + q * 8);
    }
#pragma unroll
    for (int i = 0; i < 2; ++i)
#pragma unroll
      for (int j = 0; j < 2; ++j) {
        az[i][j]  = __builtin_amdgcn_mfma_f32_16x16x32_bf16(zf[i],  w1f[j], az[i][j],  0, 0, 0);
        au0[i][j] = __builtin_amdgcn_mfma_f32_16x16x32_bf16(e0f[i], w1f[j], au0[i][j], 0, 0, 0);
        au1[i][j] = __builtin_amdgcn_mfma_f32_16x16x32_bf16(e1f[i], w1f[j], au1[i][j], 0, 0, 0);
        av0[i][j] = __builtin_amdgcn_mfma_f32_16x16x32_bf16(e0f[i], w2f[j], av0[i][j], 0, 0, 0);
        av1[i][j] = __builtin_amdgcn_mfma_f32_16x16x32_bf16(e1f[i], w2f[j], av1[i][j], 0, 0, 0);
      }
    __syncthreads();
  }

  float d0s[2][4], d1s[2][4];
#pragma unroll
  for (int i = 0; i < 2; ++i)
#pragma unroll
    for (int r = 0; r < 4; ++r) { d0s[i][r] = 0.f; d1s[i][r] = 0.f; }

#pragma unroll
  for (int j = 0; j < 2; ++j) {
    const int gcol = col0 + wn * 32 + j * 16 + r16;
    const float colb = b1[gcol] + tstage * tw1[gcol];
#pragma unroll
    for (int i = 0; i < 2; ++i) {
      const int rbase = row0 + wm * 32 + i * 16 + q * 4;   // C/D: row=quad*4+reg
#pragma unroll
      for (int r = 0; r < 4; ++r) {
        float hv = tanhf(az[i][j][r] + colb);
        hbuf[(size_t)(rbase + r) * H_N + gcol] = f2bf(hv);
        float s = 1.f - hv * hv;
        d0s[i][r] += s * au0[i][j][r] * av0[i][j][r];
        d1s[i][r] += s * au1[i][j][r] * av1[i][j][r];
      }
    }
  }
  // reduce across the 16 lanes (cols); one atomic per row
#pragma unroll
  for (int i = 0; i < 2; ++i)
#pragma unroll
    for (int r = 0; r < 4; ++r) {
      float a = d0s[i][r], b = d1s[i][r];
#pragma unroll
      for (int m = 1; m < 16; m <<= 1) { a += __shfl_xor(a, m); b += __shfl_xor(b, m); }
      if (r16 == 0) {
        int grow = row0 + wm * 32 + i * 16 + q * 4 + r;
        atomicAdd(&div0[grow], a);
        atomicAdd(&div1[grow], b);
      }
    }
}

// GEMM3 (f = h@W2 + b2) + RK38 stage epilogue on f32 state (z, ACC, T); zin bf16.
// st0: ACC=dt/8*f; T=dt*f;            zin=z+dt*f/3
// st1: ACC+=3dt/8*f; zin=z+dt*f-T/3;  T=T-dt*f
// st2: ACC+=3dt/8*f; zin=z+T+dt*f
// st3: z=z+ACC+dt/8*f; zin=z_new
template<int ST>
__global__ __launch_bounds__(256)
void k_f3(const u16* __restrict__ hbuf, const u16* __restrict__ W2T, const float* __restrict__ b2,
          float* __restrict__ z, float* __restrict__ ACC, float* __restrict__ T,
          u16* __restrict__ zin, float dt) {
  __shared__ u16 As[64 * 32];
  __shared__ u16 Bs[64 * 32];
  const int tid = threadIdx.x, wave = tid >> 6, lane = tid & 63;
  const int bm = blockIdx.x >> 3;       // D/64 = 8 col tiles
  const int bn = blockIdx.x & 7;
  const int row0 = bm * 64, col0 = bn * 64;
  const int wm = wave >> 1, wn = wave & 1, r16 = lane & 15, q = lane >> 4;
  const int srow = lane >> 2, scol = (lane & 3) * 8;

  f32x4 acc[2][2];
#pragma unroll
  for (int i = 0; i < 2; ++i)
#pragma unroll
    for (int j = 0; j < 2; ++j) acc[i][j] = (f32x4){0,0,0,0};

  for (int kt = 0; kt < 1024; kt += 32) {
    const u16* ga = hbuf + (size_t)(row0 + wave * 16 + srow) * 1024 + kt + scol;
    const u16* gb = W2T  + (size_t)(col0 + wave * 16 + srow) * 1024 + kt + scol;
    __builtin_amdgcn_global_load_lds((ga_u32*)ga, (ls_u32*)(As + wave * 512), 16, 0, 0);
    __builtin_amdgcn_global_load_lds((ga_u32*)gb, (ls_u32*)(Bs + wave * 512), 16, 0, 0);
    __syncthreads();
    s16x8 af[2], bfr[2];
#pragma unroll
    for (int i = 0; i < 2; ++i)
      af[i] = *(const s16x8*)(As + (wm * 32 + i * 16 + r16) * 32 + q * 8);
#pragma unroll
    for (int j = 0; j < 2; ++j)
      bfr[j] = *(const s16x8*)(Bs + (wn * 32 + j * 16 + r16) * 32 + q * 8);
#pragma unroll
    for (int i = 0; i < 2; ++i)
#pragma unroll
      for (int j = 0; j < 2; ++j)
        acc[i][j] = __builtin_amdgcn_mfma_f32_16x16x32_bf16(af[i], bfr[j], acc[i][j], 0, 0, 0);
    __syncthreads();
  }

#pragma unroll
  for (int j = 0; j < 2; ++j) {
    const int gcol = col0 + wn * 32 + j * 16 + r16;
    const float cb = b2[gcol];
#pragma unroll
    for (int i = 0; i < 2; ++i) {
      const int rbase = row0 + wm * 32 + i * 16 + q * 4;
#pragma unroll
      for (int r = 0; r < 4; ++r) {
        const size_t idx = (size_t)(rbase + r) * D_N + gcol;
        const float f = acc[i][j][r] + cb;
        if (ST == 0) {
          ACC[idx] = dt * 0.125f * f;
          T[idx]   = dt * f;
          zin[idx] = f2bf(z[idx] + dt * f * (1.f / 3.f));
        } else if (ST == 1) {
          float t_ = T[idx];
          ACC[idx] += 0.375f * dt * f;
          zin[idx] = f2bf(z[idx] + dt * f - t_ * (1.f / 3.f));
          T[idx]   = t_ - dt * f;
        } else if (ST == 2) {
          ACC[idx] += 0.375f * dt * f;
          zin[idx] = f2bf(z[idx] + T[idx] + dt * f);
        } else {
          float zn = z[idx] + ACC[idx] + dt * 0.125f * f;
          z[idx]   = zn;
          zin[idx] = f2bf(zn);
        }
      }
    }
  }
}

__global__ void k_divapply(float* __restrict__ lp, float* __restrict__ d0,
                           float* __restrict__ d1, float wdt) {
  int b = blockIdx.x * 256 + threadIdx.x;
  if (b >= B_N) return;
  float c = 0.5f * (d0[b] + d1[b]);
  c = fminf(fmaxf(c, -100.f), 100.f);
  lp[b] -= wdt * c;
  d0[b] = 0.f; d1[b] = 0.f;
}

// out = [rep (f32, BxD) ; logprob (f32, B)]
__global__ void k_out(const float* __restrict__ z, const float* __restrict__ lp,
                      float* __restrict__ out) {
  int b = blockIdx.x, t = threadIdx.x;
  const float* zr = z + (size_t)b * D_N;
  float ss = 0.f;
  for (int d = t; d < D_N; d += 256) {
    float v = zr[d];
    out[(size_t)b * D_N + d] = v;
    ss += v * v;
  }
  for (int off = 32; off > 0; off >>= 1) ss += __shfl_down(ss, off);
  __shared__ float red[4];
  if ((t & 63) == 0) red[t >> 6] = ss;
  __syncthreads();
  if (t == 0) out[(size_t)BD + b] = -0.5f * (red[0] + red[1] + red[2] + red[3]) + lp[b];
}

extern "C" void kernel_launch(void* const* d_in, const int* in_sizes, int n_in,
                              void* d_out, int out_size, void* d_ws, size_t ws_size,
                              hipStream_t stream) {
  const float* x   = (const float*)d_in[0];
  const float* W1  = (const float*)d_in[1];
  const float* b1  = (const float*)d_in[2];
  const float* tw1 = (const float*)d_in[3];
  const float* W2  = (const float*)d_in[4];
  const float* b2  = (const float*)d_in[5];

  // ---- workspace carve: ~22 MB ----
  const size_t NEEDED = (size_t)23 << 20;
  if (ws_size < NEEDED) {  // diagnostic: distinctive finite output instead of OOB garbage
    k_sentinel<<<(BD + B_N + 255) / 256, 256, 0, stream>>>((float*)d_out, BD + B_N);
    return;
  }
  char* w = (char*)d_ws;
  auto carve = [&](size_t bytes) { char* p = w; w += (bytes + 255) & ~(size_t)255; return p; };
  uint32_t* keys  = (uint32_t*)carve(144 * sizeof(uint32_t));
  uint32_t* ebits = (uint32_t*)carve(65536 * sizeof(uint32_t));   // 256 KB
  float* z   = (float*)carve((size_t)BD * 4);                     // 4 MB
  float* ACC = (float*)carve((size_t)BD * 4);                     // 4 MB
  float* T   = (float*)carve((size_t)BD * 4);                     // 4 MB
  u16* zin   = (u16*)carve((size_t)BD * 2);                       // 2 MB
  u16* hbuf  = (u16*)carve((size_t)B_N * H_N * 2);                // 4 MB
  u16* W1T   = (u16*)carve((size_t)H_N * D_N * 2);                // 1 MB (HxD)
  u16* W2b   = (u16*)carve((size_t)H_N * D_N * 2);                // 1 MB (HxD)
  u16* W2T   = (u16*)carve((size_t)D_N * H_N * 2);                // 1 MB (DxH)
  float* lp   = (float*)carve((size_t)B_N * 4);
  float* div0 = (float*)carve((size_t)B_N * 4);
  float* div1 = (float*)carve((size_t)B_N * 4);

  k_keysched<<<1, 1, 0, stream>>>(keys);
  k_init<<<BD / 256, 256, 0, stream>>>(x, z, zin, lp, div0, div1);
  k_cvtT<<<(D_N * H_N) / 256, 256, 0, stream>>>(W1, W1T, D_N, H_N);  // (D,H)->(H,D)
  k_cvt <<<(H_N * D_N) / 256, 256, 0, stream>>>(W2, W2b, H_N * D_N); // (H,D) direct
  k_cvtT<<<(H_N * D_N) / 256, 256, 0, stream>>>(W2, W2T, H_N, D_N);  // (H,D)->(D,H)

  const int gF1 = (B_N / 64) * (H_N / 64);   // 512
  const int gF3 = (B_N / 64) * (D_N / 64);   // 256

  for (int s = 0; s < 9; ++s) {
    float t0 = (float)s / 9.0f;
    float t1 = (float)(s + 1) / 9.0f;
    float dt = t1 - t0;
    float tst[4] = { t0, t0 + dt / 3.0f, t0 + dt * 2.0f / 3.0f, t1 };
    float wts[4] = { 1.f, 3.f, 3.f, 1.f };
    for (int st = 0; st < 4; ++st) {
      k_ebits<<<256, 256, 0, stream>>>(ebits, keys + (s * 4 + st) * 4);
      k_f1<<<gF1, 256, 0, stream>>>(zin, ebits, W1T, W2b, b1, tw1, tst[st], hbuf, div0, div1);
      if (st == 0)      k_f3<0><<<gF3, 256, 0, stream>>>(hbuf, W2T, b2, z, ACC, T, zin, dt);
      else if (st == 1) k_f3<1><<<gF3, 256, 0, stream>>>(hbuf, W2T, b2, z, ACC, T, zin, dt);
      else if (st == 2) k_f3<2><<<gF3, 256, 0, stream>>>(hbuf, W2T, b2, z, ACC, T, zin, dt);
      else              k_f3<3><<<gF3, 256, 0, stream>>>(hbuf, W2T, b2, z, ACC, T, zin, dt);
      k_divapply<<<B_N / 256, 256, 0, stream>>>(lp, div0, div1, dt * 0.125f * wts[st]);
    }
  }
  k_out<<<B_N, 256, 0, stream>>>(z, lp, (float*)d_out);
}

// Round 8
// 1664.249 us; speedup vs baseline: 1.1433x; 1.1433x over previous
//
#include <hip/hip_runtime.h>
#include <stdint.h>

// FFJORD block: B=2048, D=512, H=1024, 9 RK38 steps x 4 stages, 2 Hutchinson probes.
// f32 in/out. bf16 MFMA GEMMs, f32 accumulate, fp32 RK state.
// PRNG: JAX threefry partitionable (verified R7): split/fold = tf(key,(0,i));
// random_bits 32b = bits1^bits2 of tf(key,(0,p)); e = lsb under k2=split(folded,2)[1].
// R8: batched ebits (1 launch), bf16 e-matrices staged via global_load_lds
// (kills k_f1's VALU-bound bit expansion), divapply fused into k_f3.

#define B_N 2048
#define D_N 512
#define H_N 1024
#define BD (B_N * D_N)

typedef unsigned short u16;
typedef __attribute__((ext_vector_type(8))) short s16x8;   // 8 x bf16
typedef __attribute__((ext_vector_type(4))) float f32x4;   // MFMA accumulator

typedef __attribute__((address_space(1))) const uint32_t ga_u32;
typedef __attribute__((address_space(3))) uint32_t ls_u32;

__device__ __forceinline__ float bf2f(u16 u) {
  union { uint32_t u; float f; } c; c.u = ((uint32_t)u) << 16; return c.f;
}
__device__ __forceinline__ u16 f2bf(float f) {
  union { float f; uint32_t u; } c; c.f = f;
  uint32_t r = c.u + 0x7FFFu + ((c.u >> 16) & 1u);  // RTNE
  return (u16)(r >> 16);
}

struct U2 { uint32_t x, y; };

// Threefry-2x32, 20 rounds — KAT-verified.
__device__ __forceinline__ U2 tf2x32(uint32_t k0, uint32_t k1, uint32_t x0, uint32_t x1) {
  uint32_t k2 = k0 ^ k1 ^ 0x1BD11BDAu;
#define ROTL(a, r) (((a) << (r)) | ((a) >> (32 - (r))))
#define RND(r) { x0 += x1; x1 = ROTL(x1, r); x1 ^= x0; }
  x0 += k0; x1 += k1;
  RND(13) RND(15) RND(26) RND(6)
  x0 += k1; x1 += k2 + 1u;
  RND(17) RND(29) RND(16) RND(24)
  x0 += k2; x1 += k0 + 2u;
  RND(13) RND(15) RND(26) RND(6)
  x0 += k0; x1 += k1 + 3u;
  RND(17) RND(29) RND(16) RND(24)
  x0 += k1; x1 += k2 + 4u;
  RND(13) RND(15) RND(26) RND(6)
  x0 += k2; x1 += k0 + 5u;
#undef RND
#undef ROTL
  U2 r; r.x = x0; r.y = x1; return r;
}

// Partitionable key schedule (verified R7).
__global__ void k_keysched(uint32_t* __restrict__ ekeys) {
  if (threadIdx.x != 0 || blockIdx.x != 0) return;
  uint32_t kx = 0u, ky = 1234u;
  for (int s = 0; s < 9; ++s) {
    for (int st = 0; st < 4; ++st) {
      U2 kst = tf2x32(kx, ky, 0u, (uint32_t)(st + 1));
      for (int pr = 0; pr < 2; ++pr) {
        U2 fo = tf2x32(kst.x, kst.y, 0u, (uint32_t)pr);
        U2 k2 = tf2x32(fo.x, fo.y, 0u, 1u);
        ekeys[(s * 4 + st) * 4 + pr * 2 + 0] = k2.x;
        ekeys[(s * 4 + st) * 4 + pr * 2 + 1] = k2.y;
      }
    }
    U2 c = tf2x32(kx, ky, 0u, 0u);
    kx = c.x; ky = c.y;
  }
}

// ALL stages' packed bits in one launch: word (stage, probe, idx) covers elems
// [idx*32, idx*32+32); bit = lsb(x^y) of tf(k2, (0, p)).
__global__ void k_ebits_all(uint32_t* __restrict__ ebAll, const uint32_t* __restrict__ keys) {
  int t = blockIdx.x * 256 + threadIdx.x;   // 36*65536 threads
  int stage = t >> 16, rem = t & 65535;
  int probe = rem >> 15, idx = rem & 32767;
  uint32_t p0 = (uint32_t)idx * 32;
  uint32_t k0 = keys[stage * 4 + probe * 2], k1 = keys[stage * 4 + probe * 2 + 1];
  uint32_t bits = 0;
#pragma unroll 4
  for (int j = 0; j < 32; ++j) {
    U2 r = tf2x32(k0, k1, 0u, p0 + j);
    bits |= ((r.x ^ r.y) & 1u) << j;
  }
  ebAll[(size_t)stage * 65536 + probe * 32768 + idx] = bits;
}

// Expand a group of 4 stages' bits into bf16 +-1 matrices (ring of 4 slots).
__global__ void k_eexp(u16* __restrict__ ebf, const uint32_t* __restrict__ ebAll, int gs) {
  int t = blockIdx.x * 256 + threadIdx.x;   // 4*65536 threads
  int stage = gs + (t >> 16), rem = t & 65535;
  int probe = rem >> 15, idx = rem & 32767;
  uint32_t w = ebAll[(size_t)stage * 65536 + probe * 32768 + idx];
  uint32_t* dst = (uint32_t*)(ebf + (size_t)(stage & 3) * (2 * (size_t)BD) + (size_t)probe * BD + (size_t)idx * 32);
#pragma unroll
  for (int g4 = 0; g4 < 4; ++g4) {
    uint4 v;
    uint32_t b;
    b = w >> (g4 * 8);
    v.x = ((b & 1u) ? 0x3F80u : 0xBF80u) | (((b >> 1) & 1u) ? 0x3F800000u : 0xBF800000u);
    v.y = (((b >> 2) & 1u) ? 0x3F80u : 0xBF80u) | (((b >> 3) & 1u) ? 0x3F800000u : 0xBF800000u);
    v.z = (((b >> 4) & 1u) ? 0x3F80u : 0xBF80u) | (((b >> 5) & 1u) ? 0x3F800000u : 0xBF800000u);
    v.w = (((b >> 6) & 1u) ? 0x3F80u : 0xBF80u) | (((b >> 7) & 1u) ? 0x3F800000u : 0xBF800000u);
    ((uint4*)dst)[g4] = v;
  }
}

__global__ void k_init(const float* __restrict__ x, float* __restrict__ z, u16* __restrict__ zin,
                       float* __restrict__ lp, float* __restrict__ d0, float* __restrict__ d1) {
  int i = blockIdx.x * 256 + threadIdx.x;
  if (i < BD) { float v = x[i]; z[i] = v; zin[i] = f2bf(v); }
  if (i < B_N) { lp[i] = 0.f; d0[i] = 0.f; d1[i] = 0.f; }
}

__global__ void k_cvtT(const float* __restrict__ src, u16* __restrict__ dst, int R, int C) {
  int i = blockIdx.x * 256 + threadIdx.x;
  if (i >= R * C) return;
  int c = i / R, r = i - c * R;
  dst[i] = f2bf(src[(size_t)r * C + c]);
}
__global__ void k_cvt(const float* __restrict__ src, u16* __restrict__ dst, int n) {
  int i = blockIdx.x * 256 + threadIdx.x;
  if (i < n) dst[i] = f2bf(src[i]);
}

__global__ void k_sentinel(float* __restrict__ out, int n) {
  int i = blockIdx.x * 256 + threadIdx.x;
  if (i < n) out[i] = 12345.0f;
}

// Fused 5-product GEMM over (b,h) tiles of 64x64, K=D=512. All five operands
// staged via global_load_lds; e-tiles come pre-expanded from ebf (no VALU repack).
__global__ __launch_bounds__(256)
void k_f1(const u16* __restrict__ zin, const u16* __restrict__ e0g, const u16* __restrict__ e1g,
          const u16* __restrict__ W1T, const u16* __restrict__ W2b,
          const float* __restrict__ b1, const float* __restrict__ tw1, float tstage,
          u16* __restrict__ hbuf, float* __restrict__ div0, float* __restrict__ div1) {
  __shared__ u16 Zs[64 * 32], E0s[64 * 32], E1s[64 * 32], W1s[64 * 32], W2s[64 * 32];
  const int tid = threadIdx.x, wave = tid >> 6, lane = tid & 63;
  const int bm = blockIdx.x >> 4;        // H/64 = 16 col tiles
  const int bh = blockIdx.x & 15;
  const int row0 = bm * 64, col0 = bh * 64;
  const int wm = wave >> 1, wn = wave & 1, r16 = lane & 15, q = lane >> 4;
  const int srow = lane >> 2, scol = (lane & 3) * 8;

  f32x4 az[2][2], au0[2][2], au1[2][2], av0[2][2], av1[2][2];
#pragma unroll
  for (int i = 0; i < 2; ++i)
#pragma unroll
    for (int j = 0; j < 2; ++j) {
      az[i][j] = (f32x4){0,0,0,0}; au0[i][j] = (f32x4){0,0,0,0}; au1[i][j] = (f32x4){0,0,0,0};
      av0[i][j] = (f32x4){0,0,0,0}; av1[i][j] = (f32x4){0,0,0,0};
    }

  const size_t arow = (size_t)(row0 + wave * 16 + srow) * 512 + scol;
  const size_t brow = (size_t)(col0 + wave * 16 + srow) * 512 + scol;
  for (int kt = 0; kt < 512; kt += 32) {
    __builtin_amdgcn_global_load_lds((ga_u32*)(zin + arow + kt), (ls_u32*)(Zs  + wave * 512), 16, 0, 0);
    __builtin_amdgcn_global_load_lds((ga_u32*)(e0g + arow + kt), (ls_u32*)(E0s + wave * 512), 16, 0, 0);
    __builtin_amdgcn_global_load_lds((ga_u32*)(e1g + arow + kt), (ls_u32*)(E1s + wave * 512), 16, 0, 0);
    __builtin_amdgcn_global_load_lds((ga_u32*)(W1T + brow + kt), (ls_u32*)(W1s + wave * 512), 16, 0, 0);
    __builtin_amdgcn_global_load_lds((ga_u32*)(W2b + brow + kt), (ls_u32*)(W2s + wave * 512), 16, 0, 0);
    __syncthreads();
    s16x8 zf[2], e0f[2], e1f[2], w1f[2], w2f[2];
#pragma unroll
    for (int i = 0; i < 2; ++i) {
      const int ao = (wm * 32 + i * 16 + r16) * 32 + q * 8;
      zf[i]  = *(const s16x8*)(Zs  + ao);
      e0f[i] = *(const s16x8*)(E0s + ao);
      e1f[i] = *(const s16x8*)(E1s + ao);
    }
#pragma unroll
    for (int j = 0; j < 2; ++j) {
      const int bo = (wn * 32 + j * 16 + r16) * 32 + q * 8;
      w1f[j] = *(const s16x8*)(W1s + bo);
      w2f[j] = *(const s16x8*)(W2s + bo);
    }
#pragma unroll
    for (int i = 0; i < 2; ++i)
#pragma unroll
      for (int j = 0; j < 2; ++j) {
        az[i][j]  = __builtin_amdgcn_mfma_f32_16x16x32_bf16(zf[i],  w1f[j], az[i][j],  0, 0, 0);
        au0[i][j] = __builtin_amdgcn_mfma_f32_16x16x32_bf16(e0f[i], w1f[j], au0[i][j], 0, 0, 0);
        au1[i][j] = __builtin_amdgcn_mfma_f32_16x16x32_bf16(e1f[i], w1f[j], au1[i][j], 0, 0, 0);
        av0[i][j] = __builtin_amdgcn_mfma_f32_16x16x32_bf16(e0f[i], w2f[j], av0[i][j], 0, 0, 0);
        av1[i][j] = __builtin_amdgcn_mfma_f32_16x16x32_bf16(e1f[i], w2f[j], av1[i][j], 0, 0, 0);
      }
    __syncthreads();
  }

  float d0s[2][4], d1s[2][4];
#pragma unroll
  for (int i = 0; i < 2; ++i)
#pragma unroll
    for (int r = 0; r < 4; ++r) { d0s[i][r] = 0.f; d1s[i][r] = 0.f; }

#pragma unroll
  for (int j = 0; j < 2; ++j) {
    const int gcol = col0 + wn * 32 + j * 16 + r16;
    const float colb = b1[gcol] + tstage * tw1[gcol];
#pragma unroll
    for (int i = 0; i < 2; ++i) {
      const int rbase = row0 + wm * 32 + i * 16 + q * 4;   // C/D: row=quad*4+reg
#pragma unroll
      for (int r = 0; r < 4; ++r) {
        float hv = tanhf(az[i][j][r] + colb);
        hbuf[(size_t)(rbase + r) * H_N + gcol] = f2bf(hv);
        float s = 1.f - hv * hv;
        d0s[i][r] += s * au0[i][j][r] * av0[i][j][r];
        d1s[i][r] += s * au1[i][j][r] * av1[i][j][r];
      }
    }
  }
#pragma unroll
  for (int i = 0; i < 2; ++i)
#pragma unroll
    for (int r = 0; r < 4; ++r) {
      float a = d0s[i][r], b = d1s[i][r];
#pragma unroll
      for (int m = 1; m < 16; m <<= 1) { a += __shfl_xor(a, m); b += __shfl_xor(b, m); }
      if (r16 == 0) {
        int grow = row0 + wm * 32 + i * 16 + q * 4 + r;
        atomicAdd(&div0[grow], a);
        atomicAdd(&div1[grow], b);
      }
    }
}

// GEMM3 (f = h@W2 + b2) + RK38 stage epilogue; fused divapply prologue (bn==0).
template<int ST>
__global__ __launch_bounds__(256)
void k_f3(const u16* __restrict__ hbuf, const u16* __restrict__ W2T, const float* __restrict__ b2,
          float* __restrict__ z, float* __restrict__ ACC, float* __restrict__ T,
          u16* __restrict__ zin, float dt,
          float* __restrict__ lp, float* __restrict__ div0, float* __restrict__ div1, float wdt) {
  __shared__ u16 As[64 * 32];
  __shared__ u16 Bs[64 * 32];
  const int tid = threadIdx.x, wave = tid >> 6, lane = tid & 63;
  const int bm = blockIdx.x >> 3;       // D/64 = 8 col tiles
  const int bn = blockIdx.x & 7;
  const int row0 = bm * 64, col0 = bn * 64;
  const int wm = wave >> 1, wn = wave & 1, r16 = lane & 15, q = lane >> 4;
  const int srow = lane >> 2, scol = (lane & 3) * 8;

  if (bn == 0 && tid < 64) {  // fused divergence apply for this block's 64 rows
    int b = row0 + tid;
    float c = 0.5f * (div0[b] + div1[b]);
    c = fminf(fmaxf(c, -100.f), 100.f);
    lp[b] -= wdt * c;
    div0[b] = 0.f; div1[b] = 0.f;
  }

  f32x4 acc[2][2];
#pragma unroll
  for (int i = 0; i < 2; ++i)
#pragma unroll
    for (int j = 0; j < 2; ++j) acc[i][j] = (f32x4){0,0,0,0};

  const size_t arow = (size_t)(row0 + wave * 16 + srow) * 1024 + scol;
  const size_t brow = (size_t)(col0 + wave * 16 + srow) * 1024 + scol;
  for (int kt = 0; kt < 1024; kt += 32) {
    __builtin_amdgcn_global_load_lds((ga_u32*)(hbuf + arow + kt), (ls_u32*)(As + wave * 512), 16, 0, 0);
    __builtin_amdgcn_global_load_lds((ga_u32*)(W2T  + brow + kt), (ls_u32*)(Bs + wave * 512), 16, 0, 0);
    __syncthreads();
    s16x8 af[2], bfr[2];
#pragma unroll
    for (int i = 0; i < 2; ++i)
      af[i] = *(const s16x8*)(As + (wm * 32 + i * 16 + r16) * 32 + q * 8);
#pragma unroll
    for (int j = 0; j < 2; ++j)
      bfr[j] = *(const s16x8*)(Bs + (wn * 32 + j * 16 + r16) * 32 + q * 8);
#pragma unroll
    for (int i = 0; i < 2; ++i)
#pragma unroll
      for (int j = 0; j < 2; ++j)
        acc[i][j] = __builtin_amdgcn_mfma_f32_16x16x32_bf16(af[i], bfr[j], acc[i][j], 0, 0, 0);
    __syncthreads();
  }

#pragma unroll
  for (int j = 0; j < 2; ++j) {
    const int gcol = col0 + wn * 32 + j * 16 + r16;
    const float cb = b2[gcol];
#pragma unroll
    for (int i = 0; i < 2; ++i) {
      const int rbase = row0 + wm * 32 + i * 16 + q * 4;
#pragma unroll
      for (int r = 0; r < 4; ++r) {
        const size_t idx = (size_t)(rbase + r) * D_N + gcol;
        const float f = acc[i][j][r] + cb;
        if (ST == 0) {
          ACC[idx] = dt * 0.125f * f;
          T[idx]   = dt * f;
          zin[idx] = f2bf(z[idx] + dt * f * (1.f / 3.f));
        } else if (ST == 1) {
          float t_ = T[idx];
          ACC[idx] += 0.375f * dt * f;
          zin[idx] = f2bf(z[idx] + dt * f - t_ * (1.f / 3.f));
          T[idx]   = t_ - dt * f;
        } else if (ST == 2) {
          ACC[idx] += 0.375f * dt * f;
          zin[idx] = f2bf(z[idx] + T[idx] + dt * f);
        } else {
          float zn = z[idx] + ACC[idx] + dt * 0.125f * f;
          z[idx]   = zn;
          zin[idx] = f2bf(zn);
        }
      }
    }
  }
}

// out = [rep (f32, BxD) ; logprob (f32, B)]
__global__ void k_out(const float* __restrict__ z, const float* __restrict__ lp,
                      float* __restrict__ out) {
  int b = blockIdx.x, t = threadIdx.x;
  const float* zr = z + (size_t)b * D_N;
  float ss = 0.f;
  for (int d = t; d < D_N; d += 256) {
    float v = zr[d];
    out[(size_t)b * D_N + d] = v;
    ss += v * v;
  }
  for (int off = 32; off > 0; off >>= 1) ss += __shfl_down(ss, off);
  __shared__ float red[4];
  if ((t & 63) == 0) red[t >> 6] = ss;
  __syncthreads();
  if (t == 0) out[(size_t)BD + b] = -0.5f * (red[0] + red[1] + red[2] + red[3]) + lp[b];
}

extern "C" void kernel_launch(void* const* d_in, const int* in_sizes, int n_in,
                              void* d_out, int out_size, void* d_ws, size_t ws_size,
                              hipStream_t stream) {
  const float* x   = (const float*)d_in[0];
  const float* W1  = (const float*)d_in[1];
  const float* b1  = (const float*)d_in[2];
  const float* tw1 = (const float*)d_in[3];
  const float* W2  = (const float*)d_in[4];
  const float* b2  = (const float*)d_in[5];

  // ---- workspace carve: ~48 MB (ws is 256 MiB per harness fills) ----
  const size_t NEEDED = (size_t)50 << 20;
  if (ws_size < NEEDED) {
    k_sentinel<<<(BD + B_N + 255) / 256, 256, 0, stream>>>((float*)d_out, BD + B_N);
    return;
  }
  char* w = (char*)d_ws;
  auto carve = [&](size_t bytes) { char* p = w; w += (bytes + 255) & ~(size_t)255; return p; };
  uint32_t* keys  = (uint32_t*)carve(144 * sizeof(uint32_t));
  uint32_t* ebAll = (uint32_t*)carve((size_t)36 * 65536 * 4);     // 9.4 MB packed bits
  u16* ebf   = (u16*)carve((size_t)4 * 2 * BD * 2);               // 16 MB: 4-slot ring of bf16 e
  float* z   = (float*)carve((size_t)BD * 4);                     // 4 MB
  float* ACC = (float*)carve((size_t)BD * 4);                     // 4 MB
  float* T   = (float*)carve((size_t)BD * 4);                     // 4 MB
  u16* zin   = (u16*)carve((size_t)BD * 2);                       // 2 MB
  u16* hbuf  = (u16*)carve((size_t)B_N * H_N * 2);                // 4 MB
  u16* W1T   = (u16*)carve((size_t)H_N * D_N * 2);                // 1 MB (HxD)
  u16* W2b   = (u16*)carve((size_t)H_N * D_N * 2);                // 1 MB (HxD)
  u16* W2T   = (u16*)carve((size_t)D_N * H_N * 2);                // 1 MB (DxH)
  float* lp   = (float*)carve((size_t)B_N * 4);
  float* div0 = (float*)carve((size_t)B_N * 4);
  float* div1 = (float*)carve((size_t)B_N * 4);

  k_keysched<<<1, 1, 0, stream>>>(keys);
  k_init<<<BD / 256, 256, 0, stream>>>(x, z, zin, lp, div0, div1);
  k_cvtT<<<(D_N * H_N) / 256, 256, 0, stream>>>(W1, W1T, D_N, H_N);
  k_cvt <<<(H_N * D_N) / 256, 256, 0, stream>>>(W2, W2b, H_N * D_N);
  k_cvtT<<<(H_N * D_N) / 256, 256, 0, stream>>>(W2, W2T, H_N, D_N);
  k_ebits_all<<<(36 * 65536) / 256, 256, 0, stream>>>(ebAll, keys);

  const int gF1 = (B_N / 64) * (H_N / 64);   // 512
  const int gF3 = (B_N / 64) * (D_N / 64);   // 256

  for (int s = 0; s < 9; ++s) {
    float t0 = (float)s / 9.0f;
    float t1 = (float)(s + 1) / 9.0f;
    float dt = t1 - t0;
    float tst[4] = { t0, t0 + dt / 3.0f, t0 + dt * 2.0f / 3.0f, t1 };
    float wts[4] = { 1.f, 3.f, 3.f, 1.f };
    for (int st = 0; st < 4; ++st) {
      const int sg = s * 4 + st;
      if ((sg & 3) == 0) k_eexp<<<(4 * 65536) / 256, 256, 0, stream>>>(ebf, ebAll, sg);
      const u16* e0g = ebf + (size_t)(sg & 3) * (2 * (size_t)BD);
      const u16* e1g = e0g + BD;
      k_f1<<<gF1, 256, 0, stream>>>(zin, e0g, e1g, W1T, W2b, b1, tw1, tst[st], hbuf, div0, div1);
      const float wdt = dt * 0.125f * wts[st];
      if (st == 0)      k_f3<0><<<gF3, 256, 0, stream>>>(hbuf, W2T, b2, z, ACC, T, zin, dt, lp, div0, div1, wdt);
      else if (st == 1) k_f3<1><<<gF3, 256, 0, stream>>>(hbuf, W2T, b2, z, ACC, T, zin, dt, lp, div0, div1, wdt);
      else if (st == 2) k_f3<2><<<gF3, 256, 0, stream>>>(hbuf, W2T, b2, z, ACC, T, zin, dt, lp, div0, div1, wdt);
      else              k_f3<3><<<gF3, 256, 0, stream>>>(hbuf, W2T, b2, z, ACC, T, zin, dt, lp, div0, div1, wdt);
    }
  }
  k_out<<<B_N, 256, 0, stream>>>(z, lp, (float*)d_out);
}

// Round 9
// 1476.452 us; speedup vs baseline: 1.2887x; 1.1272x over previous
//
#include <hip/hip_runtime.h>
#include <stdint.h>

// FFJORD block: B=2048, D=512, H=1024, 9 RK38 steps x 4 stages, 2 Hutchinson probes.
// f32 in/out. bf16 MFMA GEMMs, f32 accumulate, fp32 RK state.
// PRNG: JAX threefry partitionable (verified R7).
// R9: (a) k_f1/k_f3 use single-barrier double-buffered global_load_lds prefetch
// (staging latency hidden behind MFMA of previous tile); (b) k_egen fuses
// threefry+bf16 expansion (alignbit rotates), replacing ebits_all+eexp.

#define B_N 2048
#define D_N 512
#define H_N 1024
#define BD (B_N * D_N)

typedef unsigned short u16;
typedef __attribute__((ext_vector_type(8))) short s16x8;   // 8 x bf16
typedef __attribute__((ext_vector_type(4))) float f32x4;   // MFMA accumulator

typedef __attribute__((address_space(1))) const uint32_t ga_u32;
typedef __attribute__((address_space(3))) uint32_t ls_u32;

#if __has_builtin(__builtin_amdgcn_alignbit)
#define ROTL32(x, r) __builtin_amdgcn_alignbit((x), (x), 32 - (r))
#else
#define ROTL32(x, r) (((x) << (r)) | ((x) >> (32 - (r))))
#endif

__device__ __forceinline__ float bf2f(u16 u) {
  union { uint32_t u; float f; } c; c.u = ((uint32_t)u) << 16; return c.f;
}
__device__ __forceinline__ u16 f2bf(float f) {
  union { float f; uint32_t u; } c; c.f = f;
  uint32_t r = c.u + 0x7FFFu + ((c.u >> 16) & 1u);  // RTNE
  return (u16)(r >> 16);
}

struct U2 { uint32_t x, y; };

// Threefry-2x32, 20 rounds — KAT-verified.
__device__ __forceinline__ U2 tf2x32(uint32_t k0, uint32_t k1, uint32_t x0, uint32_t x1) {
  uint32_t k2 = k0 ^ k1 ^ 0x1BD11BDAu;
#define RND(r) { x0 += x1; x1 = ROTL32(x1, r); x1 ^= x0; }
  x0 += k0; x1 += k1;
  RND(13) RND(15) RND(26) RND(6)
  x0 += k1; x1 += k2 + 1u;
  RND(17) RND(29) RND(16) RND(24)
  x0 += k2; x1 += k0 + 2u;
  RND(13) RND(15) RND(26) RND(6)
  x0 += k0; x1 += k1 + 3u;
  RND(17) RND(29) RND(16) RND(24)
  x0 += k1; x1 += k2 + 4u;
  RND(13) RND(15) RND(26) RND(6)
  x0 += k2; x1 += k0 + 5u;
#undef RND
  U2 r; r.x = x0; r.y = x1; return r;
}

// Partitionable key schedule (verified R7).
__global__ void k_keysched(uint32_t* __restrict__ ekeys) {
  if (threadIdx.x != 0 || blockIdx.x != 0) return;
  uint32_t kx = 0u, ky = 1234u;
  for (int s = 0; s < 9; ++s) {
    for (int st = 0; st < 4; ++st) {
      U2 kst = tf2x32(kx, ky, 0u, (uint32_t)(st + 1));
      for (int pr = 0; pr < 2; ++pr) {
        U2 fo = tf2x32(kst.x, kst.y, 0u, (uint32_t)pr);
        U2 k2 = tf2x32(fo.x, fo.y, 0u, 1u);
        ekeys[(s * 4 + st) * 4 + pr * 2 + 0] = k2.x;
        ekeys[(s * 4 + st) * 4 + pr * 2 + 1] = k2.y;
      }
    }
    U2 c = tf2x32(kx, ky, 0u, 0u);
    kx = c.x; ky = c.y;
  }
}

// Fused threefry + bf16 +-1 expansion for a group of 4 stages (ring of 4 slots).
// e_p = lsb(x^y) of tf(k2, (0,p)); write 8 bf16 (uint4) per 8 counters.
__global__ void k_egen(u16* __restrict__ ebf, const uint32_t* __restrict__ keys, int gs) {
  int t = blockIdx.x * 256 + threadIdx.x;   // 4*2*32768 = 262144 threads
  int stage = gs + (t >> 16), rem = t & 65535;
  int probe = rem >> 15, idx = rem & 32767;
  uint32_t p0 = (uint32_t)idx * 32;
  uint32_t k0 = keys[stage * 4 + probe * 2], k1 = keys[stage * 4 + probe * 2 + 1];
  uint4* dst = (uint4*)(ebf + (size_t)(stage & 3) * (2 * (size_t)BD) + (size_t)probe * BD + (size_t)idx * 32);
#pragma unroll
  for (int g = 0; g < 4; ++g) {
    uint32_t pr[4];
#pragma unroll
    for (int h = 0; h < 4; ++h) {
      uint32_t c0 = p0 + g * 8 + h * 2;
      U2 r0 = tf2x32(k0, k1, 0u, c0);
      U2 r1 = tf2x32(k0, k1, 0u, c0 + 1u);
      pr[h] = (((r0.x ^ r0.y) & 1u) ? 0x3F80u : 0xBF80u) |
              (((r1.x ^ r1.y) & 1u) ? 0x3F800000u : 0xBF800000u);
    }
    uint4 v; v.x = pr[0]; v.y = pr[1]; v.z = pr[2]; v.w = pr[3];
    dst[g] = v;
  }
}

__global__ void k_init(const float* __restrict__ x, float* __restrict__ z, u16* __restrict__ zin,
                       float* __restrict__ lp, float* __restrict__ d0, float* __restrict__ d1) {
  int i = blockIdx.x * 256 + threadIdx.x;
  if (i < BD) { float v = x[i]; z[i] = v; zin[i] = f2bf(v); }
  if (i < B_N) { lp[i] = 0.f; d0[i] = 0.f; d1[i] = 0.f; }
}

__global__ void k_cvtT(const float* __restrict__ src, u16* __restrict__ dst, int R, int C) {
  int i = blockIdx.x * 256 + threadIdx.x;
  if (i >= R * C) return;
  int c = i / R, r = i - c * R;
  dst[i] = f2bf(src[(size_t)r * C + c]);
}
__global__ void k_cvt(const float* __restrict__ src, u16* __restrict__ dst, int n) {
  int i = blockIdx.x * 256 + threadIdx.x;
  if (i < n) dst[i] = f2bf(src[i]);
}

__global__ void k_sentinel(float* __restrict__ out, int n) {
  int i = blockIdx.x * 256 + threadIdx.x;
  if (i < n) out[i] = 12345.0f;
}

// Fused 5-product GEMM, 64x64 tiles, K=512. Double-buffered LDS: prefetch kt+1
// issued before consuming kt; single barrier per iteration (drain overlaps MFMA).
__global__ __launch_bounds__(256)
void k_f1(const u16* __restrict__ zin, const u16* __restrict__ e0g, const u16* __restrict__ e1g,
          const u16* __restrict__ W1T, const u16* __restrict__ W2b,
          const float* __restrict__ b1, const float* __restrict__ tw1, float tstage,
          u16* __restrict__ hbuf, float* __restrict__ div0, float* __restrict__ div1) {
  __shared__ u16 S[2][5 * 2048];   // per buf: Z|E0|E1|W1|W2, each 64x32 u16
  const int tid = threadIdx.x, wave = tid >> 6, lane = tid & 63;
  const int bm = blockIdx.x >> 4;
  const int bh = blockIdx.x & 15;
  const int row0 = bm * 64, col0 = bh * 64;
  const int wm = wave >> 1, wn = wave & 1, r16 = lane & 15, q = lane >> 4;
  const int srow = lane >> 2, scol = (lane & 3) * 8;

  f32x4 az[2][2], au0[2][2], au1[2][2], av0[2][2], av1[2][2];
#pragma unroll
  for (int i = 0; i < 2; ++i)
#pragma unroll
    for (int j = 0; j < 2; ++j) {
      az[i][j] = (f32x4){0,0,0,0}; au0[i][j] = (f32x4){0,0,0,0}; au1[i][j] = (f32x4){0,0,0,0};
      av0[i][j] = (f32x4){0,0,0,0}; av1[i][j] = (f32x4){0,0,0,0};
    }

  const size_t arow = (size_t)(row0 + wave * 16 + srow) * 512 + scol;
  const size_t brow = (size_t)(col0 + wave * 16 + srow) * 512 + scol;
  auto stage = [&](int kt, int buf) {
    u16* b = &S[buf][0];
    __builtin_amdgcn_global_load_lds((ga_u32*)(zin + arow + kt), (ls_u32*)(b + 0    + wave * 512), 16, 0, 0);
    __builtin_amdgcn_global_load_lds((ga_u32*)(e0g + arow + kt), (ls_u32*)(b + 2048 + wave * 512), 16, 0, 0);
    __builtin_amdgcn_global_load_lds((ga_u32*)(e1g + arow + kt), (ls_u32*)(b + 4096 + wave * 512), 16, 0, 0);
    __builtin_amdgcn_global_load_lds((ga_u32*)(W1T + brow + kt), (ls_u32*)(b + 6144 + wave * 512), 16, 0, 0);
    __builtin_amdgcn_global_load_lds((ga_u32*)(W2b + brow + kt), (ls_u32*)(b + 8192 + wave * 512), 16, 0, 0);
  };
  stage(0, 0);
  for (int it = 0; it < 16; ++it) {
    const int buf = it & 1;
    __syncthreads();                       // drains DMA for S[buf]
    if (it + 1 < 16) stage((it + 1) * 32, buf ^ 1);  // overlaps with consume below
    const u16* b = &S[buf][0];
    s16x8 zf[2], e0f[2], e1f[2], w1f[2], w2f[2];
#pragma unroll
    for (int i = 0; i < 2; ++i) {
      const int ao = (wm * 32 + i * 16 + r16) * 32 + q * 8;
      zf[i]  = *(const s16x8*)(b + 0    + ao);
      e0f[i] = *(const s16x8*)(b + 2048 + ao);
      e1f[i] = *(const s16x8*)(b + 4096 + ao);
    }
#pragma unroll
    for (int j = 0; j < 2; ++j) {
      const int bo = (wn * 32 + j * 16 + r16) * 32 + q * 8;
      w1f[j] = *(const s16x8*)(b + 6144 + bo);
      w2f[j] = *(const s16x8*)(b + 8192 + bo);
    }
#pragma unroll
    for (int i = 0; i < 2; ++i)
#pragma unroll
      for (int j = 0; j < 2; ++j) {
        az[i][j]  = __builtin_amdgcn_mfma_f32_16x16x32_bf16(zf[i],  w1f[j], az[i][j],  0, 0, 0);
        au0[i][j] = __builtin_amdgcn_mfma_f32_16x16x32_bf16(e0f[i], w1f[j], au0[i][j], 0, 0, 0);
        au1[i][j] = __builtin_amdgcn_mfma_f32_16x16x32_bf16(e1f[i], w1f[j], au1[i][j], 0, 0, 0);
        av0[i][j] = __builtin_amdgcn_mfma_f32_16x16x32_bf16(e0f[i], w2f[j], av0[i][j], 0, 0, 0);
        av1[i][j] = __builtin_amdgcn_mfma_f32_16x16x32_bf16(e1f[i], w2f[j], av1[i][j], 0, 0, 0);
      }
  }

  float d0s[2][4], d1s[2][4];
#pragma unroll
  for (int i = 0; i < 2; ++i)
#pragma unroll
    for (int r = 0; r < 4; ++r) { d0s[i][r] = 0.f; d1s[i][r] = 0.f; }

#pragma unroll
  for (int j = 0; j < 2; ++j) {
    const int gcol = col0 + wn * 32 + j * 16 + r16;
    const float colb = b1[gcol] + tstage * tw1[gcol];
#pragma unroll
    for (int i = 0; i < 2; ++i) {
      const int rbase = row0 + wm * 32 + i * 16 + q * 4;   // C/D: row=quad*4+reg
#pragma unroll
      for (int r = 0; r < 4; ++r) {
        float hv = tanhf(az[i][j][r] + colb);
        hbuf[(size_t)(rbase + r) * H_N + gcol] = f2bf(hv);
        float s = 1.f - hv * hv;
        d0s[i][r] += s * au0[i][j][r] * av0[i][j][r];
        d1s[i][r] += s * au1[i][j][r] * av1[i][j][r];
      }
    }
  }
#pragma unroll
  for (int i = 0; i < 2; ++i)
#pragma unroll
    for (int r = 0; r < 4; ++r) {
      float a = d0s[i][r], b = d1s[i][r];
#pragma unroll
      for (int m = 1; m < 16; m <<= 1) { a += __shfl_xor(a, m); b += __shfl_xor(b, m); }
      if (r16 == 0) {
        int grow = row0 + wm * 32 + i * 16 + q * 4 + r;
        atomicAdd(&div0[grow], a);
        atomicAdd(&div1[grow], b);
      }
    }
}

// GEMM3 (f = h@W2 + b2) + RK38 epilogue; fused divapply (bn==0). Double-buffered.
template<int ST>
__global__ __launch_bounds__(256)
void k_f3(const u16* __restrict__ hbuf, const u16* __restrict__ W2T, const float* __restrict__ b2,
          float* __restrict__ z, float* __restrict__ ACC, float* __restrict__ T,
          u16* __restrict__ zin, float dt,
          float* __restrict__ lp, float* __restrict__ div0, float* __restrict__ div1, float wdt) {
  __shared__ u16 S[2][2 * 2048];   // per buf: A|B, each 64x32 u16
  const int tid = threadIdx.x, wave = tid >> 6, lane = tid & 63;
  const int bm = blockIdx.x >> 3;
  const int bn = blockIdx.x & 7;
  const int row0 = bm * 64, col0 = bn * 64;
  const int wm = wave >> 1, wn = wave & 1, r16 = lane & 15, q = lane >> 4;
  const int srow = lane >> 2, scol = (lane & 3) * 8;

  if (bn == 0 && tid < 64) {
    int b = row0 + tid;
    float c = 0.5f * (div0[b] + div1[b]);
    c = fminf(fmaxf(c, -100.f), 100.f);
    lp[b] -= wdt * c;
    div0[b] = 0.f; div1[b] = 0.f;
  }

  f32x4 acc[2][2];
#pragma unroll
  for (int i = 0; i < 2; ++i)
#pragma unroll
    for (int j = 0; j < 2; ++j) acc[i][j] = (f32x4){0,0,0,0};

  const size_t arow = (size_t)(row0 + wave * 16 + srow) * 1024 + scol;
  const size_t brow = (size_t)(col0 + wave * 16 + srow) * 1024 + scol;
  auto stage = [&](int kt, int buf) {
    u16* b = &S[buf][0];
    __builtin_amdgcn_global_load_lds((ga_u32*)(hbuf + arow + kt), (ls_u32*)(b + 0    + wave * 512), 16, 0, 0);
    __builtin_amdgcn_global_load_lds((ga_u32*)(W2T  + brow + kt), (ls_u32*)(b + 2048 + wave * 512), 16, 0, 0);
  };
  stage(0, 0);
  for (int it = 0; it < 32; ++it) {
    const int buf = it & 1;
    __syncthreads();
    if (it + 1 < 32) stage((it + 1) * 32, buf ^ 1);
    const u16* b = &S[buf][0];
    s16x8 af[2], bfr[2];
#pragma unroll
    for (int i = 0; i < 2; ++i)
      af[i] = *(const s16x8*)(b + (wm * 32 + i * 16 + r16) * 32 + q * 8);
#pragma unroll
    for (int j = 0; j < 2; ++j)
      bfr[j] = *(const s16x8*)(b + 2048 + (wn * 32 + j * 16 + r16) * 32 + q * 8);
#pragma unroll
    for (int i = 0; i < 2; ++i)
#pragma unroll
      for (int j = 0; j < 2; ++j)
        acc[i][j] = __builtin_amdgcn_mfma_f32_16x16x32_bf16(af[i], bfr[j], acc[i][j], 0, 0, 0);
  }

#pragma unroll
  for (int j = 0; j < 2; ++j) {
    const int gcol = col0 + wn * 32 + j * 16 + r16;
    const float cb = b2[gcol];
#pragma unroll
    for (int i = 0; i < 2; ++i) {
      const int rbase = row0 + wm * 32 + i * 16 + q * 4;
#pragma unroll
      for (int r = 0; r < 4; ++r) {
        const size_t idx = (size_t)(rbase + r) * D_N + gcol;
        const float f = acc[i][j][r] + cb;
        if (ST == 0) {
          ACC[idx] = dt * 0.125f * f;
          T[idx]   = dt * f;
          zin[idx] = f2bf(z[idx] + dt * f * (1.f / 3.f));
        } else if (ST == 1) {
          float t_ = T[idx];
          ACC[idx] += 0.375f * dt * f;
          zin[idx] = f2bf(z[idx] + dt * f - t_ * (1.f / 3.f));
          T[idx]   = t_ - dt * f;
        } else if (ST == 2) {
          ACC[idx] += 0.375f * dt * f;
          zin[idx] = f2bf(z[idx] + T[idx] + dt * f);
        } else {
          float zn = z[idx] + ACC[idx] + dt * 0.125f * f;
          z[idx]   = zn;
          zin[idx] = f2bf(zn);
        }
      }
    }
  }
}

// out = [rep (f32, BxD) ; logprob (f32, B)]
__global__ void k_out(const float* __restrict__ z, const float* __restrict__ lp,
                      float* __restrict__ out) {
  int b = blockIdx.x, t = threadIdx.x;
  const float* zr = z + (size_t)b * D_N;
  float ss = 0.f;
  for (int d = t; d < D_N; d += 256) {
    float v = zr[d];
    out[(size_t)b * D_N + d] = v;
    ss += v * v;
  }
  for (int off = 32; off > 0; off >>= 1) ss += __shfl_down(ss, off);
  __shared__ float red[4];
  if ((t & 63) == 0) red[t >> 6] = ss;
  __syncthreads();
  if (t == 0) out[(size_t)BD + b] = -0.5f * (red[0] + red[1] + red[2] + red[3]) + lp[b];
}

extern "C" void kernel_launch(void* const* d_in, const int* in_sizes, int n_in,
                              void* d_out, int out_size, void* d_ws, size_t ws_size,
                              hipStream_t stream) {
  const float* x   = (const float*)d_in[0];
  const float* W1  = (const float*)d_in[1];
  const float* b1  = (const float*)d_in[2];
  const float* tw1 = (const float*)d_in[3];
  const float* W2  = (const float*)d_in[4];
  const float* b2  = (const float*)d_in[5];

  const size_t NEEDED = (size_t)45 << 20;
  if (ws_size < NEEDED) {
    k_sentinel<<<(BD + B_N + 255) / 256, 256, 0, stream>>>((float*)d_out, BD + B_N);
    return;
  }
  char* w = (char*)d_ws;
  auto carve = [&](size_t bytes) { char* p = w; w += (bytes + 255) & ~(size_t)255; return p; };
  uint32_t* keys = (uint32_t*)carve(144 * sizeof(uint32_t));
  u16* ebf   = (u16*)carve((size_t)4 * 2 * BD * 2);               // 16 MB: 4-slot ring of bf16 e
  float* z   = (float*)carve((size_t)BD * 4);                     // 4 MB
  float* ACC = (float*)carve((size_t)BD * 4);                     // 4 MB
  float* T   = (float*)carve((size_t)BD * 4);                     // 4 MB
  u16* zin   = (u16*)carve((size_t)BD * 2);                       // 2 MB
  u16* hbuf  = (u16*)carve((size_t)B_N * H_N * 2);                // 4 MB
  u16* W1T   = (u16*)carve((size_t)H_N * D_N * 2);                // 1 MB (HxD)
  u16* W2b   = (u16*)carve((size_t)H_N * D_N * 2);                // 1 MB (HxD)
  u16* W2T   = (u16*)carve((size_t)D_N * H_N * 2);                // 1 MB (DxH)
  float* lp   = (float*)carve((size_t)B_N * 4);
  float* div0 = (float*)carve((size_t)B_N * 4);
  float* div1 = (float*)carve((size_t)B_N * 4);

  k_keysched<<<1, 1, 0, stream>>>(keys);
  k_init<<<BD / 256, 256, 0, stream>>>(x, z, zin, lp, div0, div1);
  k_cvtT<<<(D_N * H_N) / 256, 256, 0, stream>>>(W1, W1T, D_N, H_N);
  k_cvt <<<(H_N * D_N) / 256, 256, 0, stream>>>(W2, W2b, H_N * D_N);
  k_cvtT<<<(H_N * D_N) / 256, 256, 0, stream>>>(W2, W2T, H_N, D_N);

  const int gF1 = (B_N / 64) * (H_N / 64);   // 512
  const int gF3 = (B_N / 64) * (D_N / 64);   // 256

  for (int s = 0; s < 9; ++s) {
    float t0 = (float)s / 9.0f;
    float t1 = (float)(s + 1) / 9.0f;
    float dt = t1 - t0;
    float tst[4] = { t0, t0 + dt / 3.0f, t0 + dt * 2.0f / 3.0f, t1 };
    float wts[4] = { 1.f, 3.f, 3.f, 1.f };
    for (int st = 0; st < 4; ++st) {
      const int sg = s * 4 + st;
      if ((sg & 3) == 0) k_egen<<<1024, 256, 0, stream>>>(ebf, keys, sg);
      const u16* e0g = ebf + (size_t)(sg & 3) * (2 * (size_t)BD);
      const u16* e1g = e0g + BD;
      k_f1<<<gF1, 256, 0, stream>>>(zin, e0g, e1g, W1T, W2b, b1, tw1, tst[st], hbuf, div0, div1);
      const float wdt = dt * 0.125f * wts[st];
      if (st == 0)      k_f3<0><<<gF3, 256, 0, stream>>>(hbuf, W2T, b2, z, ACC, T, zin, dt, lp, div0, div1, wdt);
      else if (st == 1) k_f3<1><<<gF3, 256, 0, stream>>>(hbuf, W2T, b2, z, ACC, T, zin, dt, lp, div0, div1, wdt);
      else if (st == 2) k_f3<2><<<gF3, 256, 0, stream>>>(hbuf, W2T, b2, z, ACC, T, zin, dt, lp, div0, div1, wdt);
      else              k_f3<3><<<gF3, 256, 0, stream>>>(hbuf, W2T, b2, z, ACC, T, zin, dt, lp, div0, div1, wdt);
    }
  }
  k_out<<<B_N, 256, 0, stream>>>(z, lp, (float*)d_out);
}